// Round 10
// baseline (214.890 us; speedup 1.0000x reference)
//
#include <hip/hip_runtime.h>

// ---------------- types ----------------
typedef __bf16 bf16;
typedef __bf16 bf16x4 __attribute__((ext_vector_type(4)));
typedef __bf16 bf16x8 __attribute__((ext_vector_type(8)));
typedef float f32x4 __attribute__((ext_vector_type(4)));
typedef unsigned u32x4 __attribute__((ext_vector_type(4)));
typedef unsigned u32x2 __attribute__((ext_vector_type(2)));

#define AS1C(p) ((const __attribute__((address_space(1))) void*)(p))
#define AS3(p)  ((__attribute__((address_space(3))) void*)(p))

__device__ __forceinline__ void gld16(const bf16* gsrc, bf16* ldst) {
  // async global->LDS, 16 bytes/lane; LDS dest must be wave-uniform base (HW adds lane*16)
  __builtin_amdgcn_global_load_lds(AS1C(gsrc), AS3(ldst), 16, 0, 0);
}

// B=2, S=2048, D=1024, H=16, DH=64; M = B*S = 4096
// Softmax runs in the LOG2 domain: Q (and b_Q) pre-scaled by 0.125*log2(e).
#define QSCALE 0.18033688011112042f   // 0.125 * log2(e)

// ---------------- fused cast x + weight prep (one dispatch) ----------------
__global__ void prep_all(const float* __restrict__ x,
                         const float* __restrict__ WQ, const float* __restrict__ WK,
                         const float* __restrict__ WV, const float* __restrict__ WO,
                         const float* __restrict__ bQ, const float* __restrict__ bK,
                         const float* __restrict__ bV,
                         bf16* __restrict__ xb, bf16* __restrict__ Wqkv,
                         bf16* __restrict__ Wo2, float* __restrict__ biasq) {
  const int X4 = (4096 * 1024) / 4;          // float4 items of x
  const int WN = 1024 * 1024;
  const int total = X4 + 4 * WN + 3072;
  for (int i = blockIdx.x * blockDim.x + threadIdx.x; i < total; i += gridDim.x * blockDim.x) {
    if (i < X4) {
      float4 v = ((const float4*)x)[i];
      bf16x4 o;
      o[0] = (bf16)v.x; o[1] = (bf16)v.y; o[2] = (bf16)v.z; o[3] = (bf16)v.w;
      ((bf16x4*)xb)[i] = o;
    } else {
      int j = i - X4;
      if (j < WN) {
        Wqkv[j] = (bf16)(WQ[j] * QSCALE);        // fold 1/sqrt(DH) * log2e into Q
      } else if (j < 2 * WN) {
        Wqkv[j] = (bf16)WK[j - WN];
      } else if (j < 3 * WN) {
        Wqkv[j] = (bf16)WV[j - 2 * WN];
      } else if (j < 4 * WN) {
        int k = j - 3 * WN;                      // W_O flat [H][D][DH]
        int hh = k >> 16, r = k & 65535, d = r >> 6, dh = r & 63;
        Wo2[d * 1024 + hh * 64 + dh] = (bf16)WO[k];
      } else {
        int n = j - 4 * WN;
        biasq[n] = (n < 1024) ? bQ[n] * QSCALE : (n < 2048) ? bK[n - 1024] : bV[n - 2048];
      }
    }
  }
}

// ---------------- GEMM C[M,N] = A[M,K] * Bw[N,K]^T  (bf16 in, f32 acc) ----------------
// v2: double-buffered LDS (BK=64), ONE barrier per K-step, involution XOR-swizzled
// staging+reads, XCD-chunked 1D block decode.
template <int MODE>
__global__ __launch_bounds__(256, 2)
void gemm_bt(const bf16* __restrict__ A, const bf16* __restrict__ Bw,
             const float* __restrict__ bias,
             bf16* __restrict__ Qo, bf16* __restrict__ Ko, bf16* __restrict__ Vt,
             float* __restrict__ Co, int M, int N, int K) {
  __shared__ bf16 As[2][8192];               // [buf][128 rows][64 cols], swizzled chunks
  __shared__ bf16 Bs[2][8192];
  const int tid = threadIdx.x;
  const int lane = tid & 63, w = tid >> 6;
  const int wr = w >> 1, wc = w & 1;
  const int g = lane >> 4, lr = lane & 15;
  const int perx = gridDim.x >> 3;
  const int tile = (blockIdx.x & 7) * perx + (blockIdx.x >> 3);
  const int brow = (tile & 31) * 128, bcol = (tile >> 5) * 128;

  auto stage = [&](int k0, int bufi) {
#pragma unroll
    for (int it = 0; it < 4; ++it) {
      const int cb = (it * 4 + w) * 64;      // wave-uniform chunk base
      const int u = cb + lane;
      const int lc = u ^ ((u >> 3) & 7);
      const int row = lc >> 3, c8 = (lc & 7) * 8;
      gld16(A + (size_t)(brow + row) * K + k0 + c8, &As[bufi][cb * 8]);
      gld16(Bw + (size_t)(bcol + row) * K + k0 + c8, &Bs[bufi][cb * 8]);
    }
  };

  f32x4 acc[4][4] = {};
  stage(0, 0);
  const int nstep = K >> 6;

  for (int t = 0; t < nstep; ++t) {
    __syncthreads();                          // stage(t) landed; prior buf reads done
    if (t + 1 < nstep) stage((t + 1) << 6, (t + 1) & 1);   // prefetch under compute
    const bf16* as = As[t & 1];
    const bf16* bs = Bs[t & 1];
#pragma unroll
    for (int kk = 0; kk < 2; ++kk) {
      bf16x8 af[4], bfm[4];
#pragma unroll
      for (int m = 0; m < 4; ++m) {
        const int row = wr * 64 + m * 16 + lr;
        const int sl = (row * 8 + kk * 4 + g) ^ (lr & 7);
        af[m] = *(const bf16x8*)(as + sl * 8);
      }
#pragma unroll
      for (int n = 0; n < 4; ++n) {
        const int row = wc * 64 + n * 16 + lr;
        const int sl = (row * 8 + kk * 4 + g) ^ (lr & 7);
        bfm[n] = *(const bf16x8*)(bs + sl * 8);
      }
#pragma unroll
      for (int m = 0; m < 4; ++m)
#pragma unroll
        for (int n = 0; n < 4; ++n)
          acc[m][n] = __builtin_amdgcn_mfma_f32_16x16x32_bf16(af[m], bfm[n], acc[m][n], 0, 0, 0);
    }
  }

  const int row0 = brow + wr * 64;
  const int col0 = bcol + wc * 64;
#pragma unroll
  for (int m = 0; m < 4; ++m) {
#pragma unroll
    for (int n = 0; n < 4; ++n) {
      const int nidx = col0 + n * 16 + lr;
      f32x4 v = acc[m][n];
      const float bs = bias[nidx];
      if (MODE == 0) {
        const int stream = nidx >> 10;        // 0=Q 1=K 2=V (uniform per 16-lane group)
        const int j = nidx & 1023;
        const int hh = j >> 6, dh = j & 63;
        const int r0 = row0 + m * 16 + g * 4; // token row base; i = 0..3 consecutive
        const int b = r0 >> 11;
        const int p0 = r0 & 2047;
        if (stream == 2) {
          bf16x4 vv;
#pragma unroll
          for (int i = 0; i < 4; ++i) vv[i] = (bf16)(v[i] + bs);
          *(bf16x4*)(Vt + ((size_t)(b * 16 + hh) * 64 + dh) * 2048 + p0) = vv;
        } else {
          bf16* dst = (stream == 0) ? Qo : Ko;
#pragma unroll
          for (int i = 0; i < 4; ++i)
            dst[((size_t)(b * 16 + hh) * 2048 + (p0 + i)) * 64 + dh] = (bf16)(v[i] + bs);
        }
      } else {
#pragma unroll
        for (int i = 0; i < 4; ++i) {
          const int r = row0 + m * 16 + g * 4 + i;
          Co[(size_t)r * 1024 + nidx] = v[i] + bs;
        }
      }
    }
  }
}

// ---------------- causal flash attention (v7: 2 chains/wave, 128-row q-tiles) ---------
// grid 768. xcd = blk&7; s2 = blk>>3 (0..95); Gl = s2&3; u = s2>>2 (0..23);
// G = Gl*8 + xcd. q-tile jt covers rows [jt*128, +128); KV tiles 0..2jt+1 (KVBLK=64).
// u<16: SPLIT jt = 15-(u>>1), spl = u&1, halves [0,jt+1) / [jt+1,2jt+2) (equal length).
// u>=16: UNSPLIT jt = 23-u (jt<=7). Each of 4 waves owns TWO independent softmax
// chains (q rows base, base+64): K/V LDS fragments shared across chains (16 ds_reads ->
// 32 MFMA), two interleaved softmaxes give 2x ILP on the latency chain. Chain 0's
// fully-masked last diagonal tile is computed-and-masked (branchless, ~2.5% waste).
__global__ __launch_bounds__(256, 3)
void attn_kernel(const bf16* __restrict__ Qm, const bf16* __restrict__ Km,
                 const bf16* __restrict__ Vm, bf16* __restrict__ Z,
                 bf16* __restrict__ OP, float2* __restrict__ ML) {
  const int nblk = blockIdx.x;
  const int xcd = nblk & 7, s2 = nblk >> 3;  // 0..95
  const int Gl = s2 & 3, u = s2 >> 2;        // u in [0,24)
  const int G = Gl * 8 + xcd;                // (b,h) group 0..31
  const int hh = G & 15, b = G >> 4;
  const int lane = threadIdx.x & 63, w = threadIdx.x >> 6;
  const int g = lane >> 4, lr = lane & 15;
  const bool g0 = g & 1, g1 = (g >> 1) & 1;
  (void)g0; (void)g1;

  int jt, t0, t1, spl;
  if (u < 16) {
    jt = 15 - (u >> 1); spl = u & 1;
    const int mid = jt + 1;
    t0 = spl ? mid : 0;
    t1 = spl ? 2 * jt + 2 : mid;
  } else {
    jt = 23 - u; spl = -1; t0 = 0; t1 = 2 * jt + 2;
  }

  __shared__ bf16 Ks[2][4096];               // [buf][64 kv][64 dh], swizzled 16B chunks
  __shared__ bf16 Vs[2][4096];               // [buf][64 dh][64 kv], swizzled 16B chunks

  const bf16* Qb = Qm + (size_t)G * 2048 * 64;
  const bf16* Kb = Km + (size_t)G * 2048 * 64;
  const bf16* Vb = Vm + (size_t)G * 64 * 2048;

  auto stage = [&](int kv0, int bufi) {
#pragma unroll
    for (int it = 0; it < 2; ++it) {
      const int cb = w * 128 + it * 64;      // wave-uniform chunk base
      const int uu = cb + lane;
      const int lc = uu ^ ((uu >> 3) & 7);
      const int row = lc >> 3, c8 = (lc & 7) * 8;
      gld16(Kb + (size_t)(kv0 + row) * 64 + c8, &Ks[bufi][cb * 8]);
      gld16(Vb + (size_t)row * 2048 + kv0 + c8, &Vs[bufi][cb * 8]);
    }
  };

  const int qr0 = jt * 128 + w * 16 + lr;    // chain 0 q row; chain 1 = +64

  bf16x8 aq[2][2];                           // [chain][kk]
#pragma unroll
  for (int c = 0; c < 2; ++c)
#pragma unroll
    for (int kk = 0; kk < 2; ++kk)
      aq[c][kk] = *(const bf16x8*)(Qb + (size_t)(qr0 + c * 64) * 64 + kk * 32 + g * 8);

  float m_i[2] = {-1e30f, -1e30f}, l_i[2] = {0.f, 0.f};
  f32x4 oacc[2][4] = {};                     // [chain][n]: O^T rows dh=n*16+4g+i, col q

  int buf = 0;
  stage(t0 * 64, 0);
  __syncthreads();

  for (int t = t0; t < t1; ++t) {
    if (t + 1 < t1) stage((t + 1) * 64, buf ^ 1);  // prefetch next tile
    const int kv0 = t * 64;
    const bool diag = (t >= 2 * jt);

    // QK^T swapped, both chains share each K fragment
    f32x4 s[2][4] = {};
#pragma unroll
    for (int kk = 0; kk < 2; ++kk) {
#pragma unroll
      for (int n = 0; n < 4; ++n) {
        const int r = n * 16 + lr;
        const int sl = (r * 8 + kk * 4 + g) ^ (r & 7);
        bf16x8 bk = *(const bf16x8*)(&Ks[buf][sl * 8]);
        s[0][n] = __builtin_amdgcn_mfma_f32_16x16x32_bf16(bk, aq[0][kk], s[0][n], 0, 0, 0);
        s[1][n] = __builtin_amdgcn_mfma_f32_16x16x32_bf16(bk, aq[1][kk], s[1][n], 0, 0, 0);
      }
    }
    if (diag) {                              // causal mask (last two tiles of the q-tile)
#pragma unroll
      for (int c = 0; c < 2; ++c) {
        const int qg = qr0 + c * 64;
#pragma unroll
        for (int n = 0; n < 4; ++n)
#pragma unroll
          for (int i = 0; i < 4; ++i)
            if (kv0 + n * 16 + g * 4 + i > qg) s[c][n][i] = -1e9f;
      }
    }

    // two independent in-lane softmaxes (log2 domain, defer-max) -> PV B-frags
    bf16x8 pb[2][2];
#pragma unroll
    for (int c = 0; c < 2; ++c) {
      float tm = fmaxf(fmaxf(fmaxf(s[c][0][0], s[c][0][1]), fmaxf(s[c][0][2], s[c][0][3])),
                       fmaxf(fmaxf(s[c][1][0], s[c][1][1]), fmaxf(s[c][1][2], s[c][1][3])));
      tm = fmaxf(tm, fmaxf(fmaxf(fmaxf(s[c][2][0], s[c][2][1]), fmaxf(s[c][2][2], s[c][2][3])),
                           fmaxf(fmaxf(s[c][3][0], s[c][3][1]), fmaxf(s[c][3][2], s[c][3][3]))));
      tm = fmaxf(tm, __shfl_xor(tm, 16));
      tm = fmaxf(tm, __shfl_xor(tm, 32));
      if (!__all(tm <= m_i[c] + 12.f)) {     // rescale only when max grew materially
        const float mn = fmaxf(m_i[c], tm);
        const float al = exp2f(m_i[c] - mn);
        m_i[c] = mn;
        l_i[c] *= al;
#pragma unroll
        for (int n = 0; n < 4; ++n)
#pragma unroll
          for (int i = 0; i < 4; ++i) oacc[c][n][i] *= al;
      }
#pragma unroll
      for (int n = 0; n < 4; ++n)
#pragma unroll
        for (int i = 0; i < 4; ++i) s[c][n][i] = exp2f(s[c][n][i] - m_i[c]);
      float ts = ((s[c][0][0] + s[c][0][1]) + (s[c][0][2] + s[c][0][3])) +
                 ((s[c][1][0] + s[c][1][1]) + (s[c][1][2] + s[c][1][3])) +
                 ((s[c][2][0] + s[c][2][1]) + (s[c][2][2] + s[c][2][3])) +
                 ((s[c][3][0] + s[c][3][1]) + (s[c][3][2] + s[c][3][3]));
      ts += __shfl_xor(ts, 16);
      ts += __shfl_xor(ts, 32);
      l_i[c] += ts;

      // pack to bf16 pairs: U[n*2+h] = key-pair c5..c0: (c4c3=n, c2c1=g, c0=h)
      unsigned U[8];
#pragma unroll
      for (int n = 0; n < 4; ++n)
#pragma unroll
        for (int h = 0; h < 2; ++h) {
          unsigned lo = (unsigned)__builtin_bit_cast(unsigned short, (bf16)s[c][n][2 * h]);
          unsigned hi = (unsigned)__builtin_bit_cast(unsigned short, (bf16)s[c][n][2 * h + 1]);
          U[n * 2 + h] = lo | (hi << 16);
        }
      unsigned v2_000, v2_001, v2_010, v2_011, v2_100, v2_101, v2_110, v2_111;
#if __has_builtin(__builtin_amdgcn_permlane32_swap)
      {
        u32x2 pA0 = __builtin_amdgcn_permlane32_swap(U[0], U[2], false, false);
        u32x2 pA1 = __builtin_amdgcn_permlane32_swap(U[1], U[3], false, false);
        u32x2 pA2 = __builtin_amdgcn_permlane32_swap(U[4], U[6], false, false);
        u32x2 pA3 = __builtin_amdgcn_permlane32_swap(U[5], U[7], false, false);
        v2_000 = pA0[0]; v2_010 = pA0[1];
        v2_001 = pA1[0]; v2_011 = pA1[1];
        v2_100 = pA2[0]; v2_110 = pA2[1];
        v2_101 = pA3[0]; v2_111 = pA3[1];
      }
#else
      {
        const bool G1 = (lane >> 5) & 1;
        unsigned rA0 = (unsigned)__shfl_xor((int)(G1 ? U[0] : U[2]), 32);
        unsigned rA1 = (unsigned)__shfl_xor((int)(G1 ? U[1] : U[3]), 32);
        unsigned rA2 = (unsigned)__shfl_xor((int)(G1 ? U[4] : U[6]), 32);
        unsigned rA3 = (unsigned)__shfl_xor((int)(G1 ? U[5] : U[7]), 32);
        v2_000 = G1 ? rA0 : U[0];
        v2_001 = G1 ? rA1 : U[1];
        v2_010 = G1 ? U[2] : rA0;
        v2_011 = G1 ? U[3] : rA1;
        v2_100 = G1 ? rA2 : U[4];
        v2_101 = G1 ? rA3 : U[5];
        v2_110 = G1 ? U[6] : rA2;
        v2_111 = G1 ? U[7] : rA3;
      }
#endif
      u32x4 t0v, t1v;
#if __has_builtin(__builtin_amdgcn_permlane16_swap)
      {
        u32x2 pB0 = __builtin_amdgcn_permlane16_swap(v2_000, v2_010, false, false);
        u32x2 pB1 = __builtin_amdgcn_permlane16_swap(v2_001, v2_011, false, false);
        u32x2 pB2 = __builtin_amdgcn_permlane16_swap(v2_100, v2_110, false, false);
        u32x2 pB3 = __builtin_amdgcn_permlane16_swap(v2_101, v2_111, false, false);
        t0v[0] = pB0[0]; t0v[2] = pB0[1];
        t0v[1] = pB1[0]; t0v[3] = pB1[1];
        t1v[0] = pB2[0]; t1v[2] = pB2[1];
        t1v[1] = pB3[0]; t1v[3] = pB3[1];
      }
#else
      {
        const bool G0 = (lane >> 4) & 1;
        unsigned rB0 = (unsigned)__shfl_xor((int)(G0 ? v2_000 : v2_010), 16);
        unsigned rB1 = (unsigned)__shfl_xor((int)(G0 ? v2_001 : v2_011), 16);
        unsigned rB2 = (unsigned)__shfl_xor((int)(G0 ? v2_100 : v2_110), 16);
        unsigned rB3 = (unsigned)__shfl_xor((int)(G0 ? v2_101 : v2_111), 16);
        t0v[0] = G0 ? rB0 : v2_000;
        t0v[1] = G0 ? rB1 : v2_001;
        t0v[2] = G0 ? v2_010 : rB0;
        t0v[3] = G0 ? v2_011 : rB1;
        t1v[0] = G0 ? rB2 : v2_100;
        t1v[1] = G0 ? rB3 : v2_101;
        t1v[2] = G0 ? v2_110 : rB2;
        t1v[3] = G0 ? v2_111 : rB3;
      }
#endif
      pb[c][0] = __builtin_bit_cast(bf16x8, t0v);
      pb[c][1] = __builtin_bit_cast(bf16x8, t1v);
    }

    // PV swapped, both chains share each V fragment
#pragma unroll
    for (int kk = 0; kk < 2; ++kk) {
#pragma unroll
      for (int n = 0; n < 4; ++n) {
        const int r = n * 16 + lr;
        const int sl = (r * 8 + kk * 4 + g) ^ (r & 7);
        bf16x8 av = *(const bf16x8*)(&Vs[buf][sl * 8]);
        oacc[0][n] = __builtin_amdgcn_mfma_f32_16x16x32_bf16(av, pb[0][kk], oacc[0][n], 0, 0, 0);
        oacc[1][n] = __builtin_amdgcn_mfma_f32_16x16x32_bf16(av, pb[1][kk], oacc[1][n], 0, 0, 0);
      }
    }
    __syncthreads();                         // prefetch landed + LDS safe to overwrite
    buf ^= 1;
  }

  if (u < 16) {
    // split block: unnormalized partials (bf16) + (m,l) [m in log2 domain]
#pragma unroll
    for (int c = 0; c < 2; ++c) {
      const int pr = G * 1024 + (jt - 8) * 128 + c * 64 + w * 16 + lr;
      bf16* oprow = OP + (size_t)(spl * 32768 + pr) * 64;
#pragma unroll
      for (int n = 0; n < 4; ++n) {
        bf16x4 o4;
#pragma unroll
        for (int i = 0; i < 4; ++i) o4[i] = (bf16)oacc[c][n][i];
        *(bf16x4*)(oprow + n * 16 + g * 4) = o4;
      }
      if (lane < 16) ML[spl * 32768 + pr] = make_float2(m_i[c], l_i[c]);
    }
  } else {
#pragma unroll
    for (int c = 0; c < 2; ++c) {
      const float li = 1.f / l_i[c];
      const int qg = qr0 + c * 64;
      bf16* zrow = Z + ((size_t)(b * 2048 + qg) * 16 + hh) * 64;
#pragma unroll
      for (int n = 0; n < 4; ++n) {
        bf16x4 o4;
#pragma unroll
        for (int i = 0; i < 4; ++i) o4[i] = (bf16)(oacc[c][n][i] * li);
        *(bf16x4*)(zrow + n * 16 + g * 4) = o4;  // dh = n*16 + 4g + i
      }
    }
  }
}

// ---------------- combine split partials into Z (rows q >= 1024 of each (b,h)) --------
__global__ __launch_bounds__(256)
void combine_kernel(const bf16* __restrict__ OP, const float2* __restrict__ ML,
                    bf16* __restrict__ Z) {
  const int id = blockIdx.x * 256 + threadIdx.x;   // 262144 = 32768 rows x 8 chunks
  const int pr = id >> 3, d8 = id & 7;
  const float2 ml0 = ML[pr], ml1 = ML[32768 + pr];
  const float m = fmaxf(ml0.x, ml1.x);
  const float w0 = exp2f(ml0.x - m), w1 = exp2f(ml1.x - m);   // log2-domain maxes
  const float inv = 1.f / (ml0.y * w0 + ml1.y * w1);
  const bf16x8 a = *(const bf16x8*)(OP + (size_t)pr * 64 + d8 * 8);
  const bf16x8 c = *(const bf16x8*)(OP + ((size_t)32768 + pr) * 64 + d8 * 8);
  bf16x8 o;
#pragma unroll
  for (int j = 0; j < 8; ++j)
    o[j] = (bf16)(((float)a[j] * w0 + (float)c[j] * w1) * inv);
  const int bh = pr >> 10, qr = pr & 1023;
  const int bb = bh >> 4, hq = bh & 15;
  *(bf16x8*)(Z + (((size_t)(bb * 2048 + 1024 + qr)) * 16 + hq) * 64 + d8 * 8) = o;
}

// ---------------- launcher ----------------
extern "C" void kernel_launch(void* const* d_in, const int* in_sizes, int n_in,
                              void* d_out, int out_size, void* d_ws, size_t ws_size,
                              hipStream_t stream) {
  const float* x  = (const float*)d_in[0];
  const float* WQ = (const float*)d_in[1];
  const float* WK = (const float*)d_in[2];
  const float* WV = (const float*)d_in[3];
  const float* WO = (const float*)d_in[4];
  const float* bQ = (const float*)d_in[5];
  const float* bK = (const float*)d_in[6];
  const float* bV = (const float*)d_in[7];
  const float* bO = (const float*)d_in[8];
  float* out = (float*)d_out;

  char* ws = (char*)d_ws;
  bf16* xb    = (bf16*)(ws);                        // 8 MB  [4096,1024]   (reused: OP)
  bf16* Wqkv  = (bf16*)(ws + (8u << 20));           // 6 MB  [3072,1024]   (reused: ML)
  bf16* Wo2   = (bf16*)(ws + (14u << 20));          // 2 MB  [1024,1024]
  bf16* Qb    = (bf16*)(ws + (16u << 20));          // 8 MB  [B,H,S,DH]
  bf16* Kb    = (bf16*)(ws + (24u << 20));          // 8 MB  [B,H,S,DH]
  bf16* Vtb   = (bf16*)(ws + (32u << 20));          // 8 MB  [B,H,DH,S]
  bf16* Zb    = (bf16*)(ws + (40u << 20));          // 8 MB  [4096,1024]
  float* biasq = (float*)(ws + (48u << 20));        // 12 KB [3072]
  // attn partials overlay regions consumed before attn runs (stream-ordered):
  bf16* OP    = (bf16*)(ws);                        // 8 MB  [2][32768][64] bf16
  float2* ML  = (float2*)(ws + (8u << 20));         // 0.5MB [2][32768] (m,l)

  prep_all<<<2048, 256, 0, stream>>>(x, WQ, WK, WV, WO, bQ, bK, bV, xb, Wqkv, Wo2, biasq);
  gemm_bt<0><<<768, 256, 0, stream>>>(xb, Wqkv, biasq, Qb, Kb, Vtb, nullptr,
                                      4096, 3072, 1024);
  attn_kernel<<<768, 256, 0, stream>>>(Qb, Kb, Vtb, Zb, OP, ML);
  combine_kernel<<<1024, 256, 0, stream>>>(OP, ML, Zb);
  gemm_bt<1><<<256, 256, 0, stream>>>(Zb, Wo2, bO, nullptr, nullptr, nullptr, out,
                                      4096, 1024, 1024);
}

// Round 11
// 203.871 us; speedup vs baseline: 1.0540x; 1.0540x over previous
//
#include <hip/hip_runtime.h>

// ---------------- types ----------------
typedef __bf16 bf16;
typedef __bf16 bf16x4 __attribute__((ext_vector_type(4)));
typedef __bf16 bf16x8 __attribute__((ext_vector_type(8)));
typedef float f32x4 __attribute__((ext_vector_type(4)));
typedef unsigned u32x4 __attribute__((ext_vector_type(4)));

#define AS1C(p) ((const __attribute__((address_space(1))) void*)(p))
#define AS3(p)  ((__attribute__((address_space(3))) void*)(p))

__device__ __forceinline__ void gld16(const bf16* gsrc, bf16* ldst) {
  // async global->LDS, 16 bytes/lane; LDS dest must be wave-uniform base (HW adds lane*16)
  __builtin_amdgcn_global_load_lds(AS1C(gsrc), AS3(ldst), 16, 0, 0);
}

// B=2, S=2048, D=1024, H=16, DH=64; M = B*S = 4096

// ---------------- fused cast x + weight prep (one dispatch) ----------------
__global__ void prep_all(const float* __restrict__ x,
                         const float* __restrict__ WQ, const float* __restrict__ WK,
                         const float* __restrict__ WV, const float* __restrict__ WO,
                         const float* __restrict__ bQ, const float* __restrict__ bK,
                         const float* __restrict__ bV,
                         bf16* __restrict__ xb, bf16* __restrict__ Wqkv,
                         bf16* __restrict__ Wo2, float* __restrict__ biasq) {
  const int X4 = (4096 * 1024) / 4;          // float4 items of x
  const int WN = 1024 * 1024;
  const int total = X4 + 4 * WN + 3072;
  for (int i = blockIdx.x * blockDim.x + threadIdx.x; i < total; i += gridDim.x * blockDim.x) {
    if (i < X4) {
      float4 v = ((const float4*)x)[i];
      bf16x4 o;
      o[0] = (bf16)v.x; o[1] = (bf16)v.y; o[2] = (bf16)v.z; o[3] = (bf16)v.w;
      ((bf16x4*)xb)[i] = o;
    } else {
      int j = i - X4;
      if (j < WN) {
        Wqkv[j] = (bf16)(WQ[j] * 0.125f);        // fold 1/sqrt(DH) into Q
      } else if (j < 2 * WN) {
        Wqkv[j] = (bf16)WK[j - WN];
      } else if (j < 3 * WN) {
        Wqkv[j] = (bf16)WV[j - 2 * WN];
      } else if (j < 4 * WN) {
        int k = j - 3 * WN;                      // W_O flat [H][D][DH]
        int hh = k >> 16, r = k & 65535, d = r >> 6, dh = r & 63;
        Wo2[d * 1024 + hh * 64 + dh] = (bf16)WO[k];
      } else {
        int n = j - 4 * WN;
        biasq[n] = (n < 1024) ? bQ[n] * 0.125f : (n < 2048) ? bK[n - 1024] : bV[n - 2048];
      }
    }
  }
}

// ---------------- GEMM C[M,N] = A[M,K] * Bw[N,K]^T  (bf16 in, f32 acc) ----------------
// v3: persistent blocks (1-2 tiles each, XCD-balanced), double-buffered LDS (BK=64),
// counted-vmcnt pipeline: raw s_barrier pairs + s_waitcnt vmcnt(8) keeps one stage in
// flight across barriers (T4); depth-2 prefetch (stage t+2 issued after read-done
// barrier); next-tile stages issued BEFORE the epilogue so stores hide their latency.
// Involution XOR-swizzled staging+reads (conflict-free ds_read_b128).
// MODE 0: QKV projection -> scatter Q[B,H,S,DH], K[B,H,S,DH], Vt[B,H,DH,S] (bf16, +bias)
// MODE 1: out projection -> Co[M,N] f32 (+bias)
template <int MODE>
__global__ __launch_bounds__(256, 2)
void gemm_bt(const bf16* __restrict__ A, const bf16* __restrict__ Bw,
             const float* __restrict__ bias,
             bf16* __restrict__ Qo, bf16* __restrict__ Ko, bf16* __restrict__ Vt,
             float* __restrict__ Co, int M, int N, int K) {
  __shared__ bf16 As[2][8192];               // [buf][128 rows][64 cols], swizzled chunks
  __shared__ bf16 Bs[2][8192];
  const int tid = threadIdx.x;
  const int lane = tid & 63, w = tid >> 6;
  const int wr = w >> 1, wc = w & 1;
  const int g = lane >> 4, lr = lane & 15;
  const int nstep = K >> 6;                  // 16

  // persistent-tile list: tiles[0] XCD-chunked over the first 512 (or 256) tiles;
  // MODE 0 has 768 tiles -> blocks 0..255 take a second, XCD-balanced tile.
  const int xcd = blockIdx.x & 7, loc = blockIdx.x >> 3;
  int tiles[2];
  int nt = 1;
  tiles[0] = xcd * (gridDim.x >> 3) + loc;
  if (MODE == 0 && blockIdx.x < 256) { tiles[1] = 512 + xcd * 32 + loc; nt = 2; }

  // linear LDS dest + involution-swizzled global source (chunk u receives logical
  // chunk u ^ ((u>>3)&7)); read side applies the same involution.
  auto stageT = [&](int tile, int t, int bufi) {
    const int br = (tile & 31) * 128, bc = (tile >> 5) * 128;
    const int k0 = t << 6;
#pragma unroll
    for (int it = 0; it < 4; ++it) {
      const int cb = (it * 4 + w) * 64;      // wave-uniform chunk base
      const int u = cb + lane;
      const int lc = u ^ ((u >> 3) & 7);
      const int row = lc >> 3, c8 = (lc & 7) * 8;
      gld16(A + (size_t)(br + row) * K + k0 + c8, &As[bufi][cb * 8]);
      gld16(Bw + (size_t)(bc + row) * K + k0 + c8, &Bs[bufi][cb * 8]);
    }
  };

  stageT(tiles[0], 0, 0);                    // prologue: depth-2 prefetch
  stageT(tiles[0], 1, 1);

  for (int ti = 0; ti < nt; ++ti) {
    const int tile = tiles[ti];
    const int brow = (tile & 31) * 128, bcol = (tile >> 5) * 128;
    f32x4 acc[4][4] = {};

    for (int t = 0; t < nstep; ++t) {
      // wait my stage(t) landed (stage(t+1)'s 8 loads may stay in flight)
      if (t + 1 < nstep) { asm volatile("s_waitcnt vmcnt(8)" ::: "memory"); }
      else               { asm volatile("s_waitcnt vmcnt(0)" ::: "memory"); }
      __builtin_amdgcn_sched_barrier(0);
      __builtin_amdgcn_s_barrier();          // all waves' stage(t) landed -> buf ready

      const bf16* as = As[t & 1];
      const bf16* bs = Bs[t & 1];
#pragma unroll
      for (int kk = 0; kk < 2; ++kk) {
        bf16x8 af[4], bfm[4];
#pragma unroll
        for (int m = 0; m < 4; ++m) {
          const int row = wr * 64 + m * 16 + lr;
          const int sl = (row * 8 + kk * 4 + g) ^ (lr & 7);
          af[m] = *(const bf16x8*)(as + sl * 8);
        }
#pragma unroll
        for (int n = 0; n < 4; ++n) {
          const int row = wc * 64 + n * 16 + lr;
          const int sl = (row * 8 + kk * 4 + g) ^ (lr & 7);
          bfm[n] = *(const bf16x8*)(bs + sl * 8);
        }
#pragma unroll
        for (int m = 0; m < 4; ++m)
#pragma unroll
          for (int n = 0; n < 4; ++n)
            acc[m][n] = __builtin_amdgcn_mfma_f32_16x16x32_bf16(af[m], bfm[n], acc[m][n], 0, 0, 0);
      }
      __builtin_amdgcn_sched_barrier(0);
      __builtin_amdgcn_s_barrier();          // all waves done READING buf[t&1]
      if (t + 2 < nstep) stageT(tile, t + 2, t & 1);   // overwrite now safe
    }

    // prefetch next tile's first two K-steps under the epilogue stores
    if (ti + 1 < nt) { stageT(tiles[ti + 1], 0, 0); stageT(tiles[ti + 1], 1, 1); }

    const int row0 = brow + wr * 64;
    const int col0 = bcol + wc * 64;
#pragma unroll
    for (int m = 0; m < 4; ++m) {
#pragma unroll
      for (int n = 0; n < 4; ++n) {
        const int nidx = col0 + n * 16 + lr;
        f32x4 v = acc[m][n];
        const float bs = bias[nidx];
        if (MODE == 0) {
          const int stream = nidx >> 10;      // 0=Q 1=K 2=V (uniform per 16-lane group)
          const int j = nidx & 1023;
          const int hh = j >> 6, dh = j & 63;
          const int r0 = row0 + m * 16 + g * 4;
          const int b = r0 >> 11;
          const int p0 = r0 & 2047;
          if (stream == 2) {
            bf16x4 vv;
#pragma unroll
            for (int i = 0; i < 4; ++i) vv[i] = (bf16)(v[i] + bs);
            *(bf16x4*)(Vt + ((size_t)(b * 16 + hh) * 64 + dh) * 2048 + p0) = vv;
          } else {
            bf16* dst = (stream == 0) ? Qo : Ko;
#pragma unroll
            for (int i = 0; i < 4; ++i)
              dst[((size_t)(b * 16 + hh) * 2048 + (p0 + i)) * 64 + dh] = (bf16)(v[i] + bs);
          }
        } else {
#pragma unroll
          for (int i = 0; i < 4; ++i) {
            const int r = row0 + m * 16 + g * 4 + i;
            Co[(size_t)r * 1024 + nidx] = v[i] + bs;
          }
        }
      }
    }
  }
}

// ---------------- causal flash attention (v5, round-8 proven: swapped-operand, -------
// in-register softmax, selective KV-split). grid 1536 flat. xcd = blk&7; s2 = blk>>3;
// Gl = s2&3; u = s2>>2 (0..47); G = Gl*8 + xcd. u<32: SPLIT qt = 31-(u>>1), spl = u&1;
// u>=32: UNSPLIT qt = 47-u. Unnormalized partials to OP/ML for split blocks.
__global__ __launch_bounds__(256, 4)
void attn_kernel(const bf16* __restrict__ Qm, const bf16* __restrict__ Km,
                 const bf16* __restrict__ Vm, bf16* __restrict__ Z,
                 bf16* __restrict__ OP, float2* __restrict__ ML) {
  const int nblk = blockIdx.x;
  const int xcd = nblk & 7, s2 = nblk >> 3;
  const int Gl = s2 & 3, u = s2 >> 2;        // u in [0,48)
  const int G = Gl * 8 + xcd;                // (b,h) group 0..31
  const int hh = G & 15, b = G >> 4;
  const int lane = threadIdx.x & 63, w = threadIdx.x >> 6;
  const int g = lane >> 4, lr = lane & 15;
  const bool g0 = g & 1, g1 = (g >> 1) & 1;

  int qt, t0, t1, spl;
  if (u < 32) {
    qt = 31 - (u >> 1); spl = u & 1;
    const int T = qt + 1, mid = (T + 1) >> 1;
    t0 = spl ? mid : 0; t1 = spl ? T : mid;
  } else {
    qt = 47 - u; spl = -1; t0 = 0; t1 = qt + 1;
  }

  __shared__ bf16 Ks[2][4096];               // [buf][64 kv][64 dh], swizzled 16B chunks
  __shared__ bf16 Vs[2][4096];               // [buf][64 dh][64 kv], swizzled 16B chunks

  const bf16* Qb = Qm + (size_t)G * 2048 * 64;
  const bf16* Kb = Km + (size_t)G * 2048 * 64;
  const bf16* Vb = Vm + (size_t)G * 64 * 2048;

  auto stage = [&](int kv0, int bufi) {
#pragma unroll
    for (int it = 0; it < 2; ++it) {
      const int cb = w * 128 + it * 64;      // wave-uniform chunk base
      const int uu = cb + lane;
      const int lc = uu ^ ((uu >> 3) & 7);
      const int row = lc >> 3, c8 = (lc & 7) * 8;
      gld16(Kb + (size_t)(kv0 + row) * 64 + c8, &Ks[bufi][cb * 8]);
      gld16(Vb + (size_t)row * 2048 + kv0 + c8, &Vs[bufi][cb * 8]);
    }
  };

  const int q0w = qt * 64 + w * 16;
  const int qg = q0w + lr;                   // this lane's q row (swapped layout: col=q=lr)

  bf16x8 aq[2];                              // Q[q=lr][k-slice g] — serves as B-fragment
#pragma unroll
  for (int kk = 0; kk < 2; ++kk)
    aq[kk] = *(const bf16x8*)(Qb + (size_t)qg * 64 + kk * 32 + g * 8);

  float m_i = -1e30f, l_i = 0.f;
  f32x4 oacc[4] = {};                        // oacc[n]: O^T rows dh = n*16+4g+i, col q=lr

  int buf = 0;
  stage(t0 * 64, 0);
  __syncthreads();

  for (int t = t0; t < t1; ++t) {
    if (t + 1 < t1) stage((t + 1) * 64, buf ^ 1);  // prefetch next tile
    const int kv0 = t * 64;

    // QK^T swapped: s[n] rows = keys n*16+4g+i, col = q = lr
    f32x4 s[4] = {};
#pragma unroll
    for (int kk = 0; kk < 2; ++kk) {
#pragma unroll
      for (int n = 0; n < 4; ++n) {
        const int r = n * 16 + lr;
        const int sl = (r * 8 + kk * 4 + g) ^ (r & 7);
        bf16x8 bk = *(const bf16x8*)(&Ks[buf][sl * 8]);
        s[n] = __builtin_amdgcn_mfma_f32_16x16x32_bf16(bk, aq[kk], s[n], 0, 0, 0);
      }
    }
    if (t == qt) {                           // causal mask on diagonal tile
#pragma unroll
      for (int n = 0; n < 4; ++n)
#pragma unroll
        for (int i = 0; i < 4; ++i)
          if (kv0 + n * 16 + g * 4 + i > qg) s[n][i] = -1e9f;
    }

    // in-lane softmax for q = lr (16 keys/lane, cross-g via 2 shfl)
    float tm = fmaxf(fmaxf(fmaxf(s[0][0], s[0][1]), fmaxf(s[0][2], s[0][3])),
                     fmaxf(fmaxf(s[1][0], s[1][1]), fmaxf(s[1][2], s[1][3])));
    tm = fmaxf(tm, fmaxf(fmaxf(fmaxf(s[2][0], s[2][1]), fmaxf(s[2][2], s[2][3])),
                         fmaxf(fmaxf(s[3][0], s[3][1]), fmaxf(s[3][2], s[3][3]))));
    tm = fmaxf(tm, __shfl_xor(tm, 16));
    tm = fmaxf(tm, __shfl_xor(tm, 32));
    const float mn = fmaxf(m_i, tm);
    const float al = __expf(m_i - mn);
    m_i = mn;
#pragma unroll
    for (int n = 0; n < 4; ++n)
#pragma unroll
      for (int i = 0; i < 4; ++i) s[n][i] = __expf(s[n][i] - mn);
    float ts = ((s[0][0] + s[0][1]) + (s[0][2] + s[0][3])) +
               ((s[1][0] + s[1][1]) + (s[1][2] + s[1][3])) +
               ((s[2][0] + s[2][1]) + (s[2][2] + s[2][3])) +
               ((s[3][0] + s[3][1]) + (s[3][2] + s[3][3]));
    ts += __shfl_xor(ts, 16);
    ts += __shfl_xor(ts, 32);
    l_i = l_i * al + ts;
#pragma unroll
    for (int n = 0; n < 4; ++n)
#pragma unroll
      for (int i = 0; i < 4; ++i) oacc[n][i] *= al;

    // pack P to bf16 pairs: U[n*2+h] = keys {16n+4g+2h, +1} (key-pair c = 8n+2g+h)
    unsigned U[8];
#pragma unroll
    for (int n = 0; n < 4; ++n)
#pragma unroll
      for (int h = 0; h < 2; ++h) {
        unsigned lo = (unsigned)__builtin_bit_cast(unsigned short, (bf16)s[n][2 * h]);
        unsigned hi = (unsigned)__builtin_bit_cast(unsigned short, (bf16)s[n][2 * h + 1]);
        U[n * 2 + h] = lo | (hi << 16);
      }
    // butterfly stage A (xor 32, toggles g1): send slots with n&1 == !g1
    unsigned rA0 = (unsigned)__shfl_xor((int)(g1 ? U[0] : U[2]), 32);
    unsigned rA1 = (unsigned)__shfl_xor((int)(g1 ? U[1] : U[3]), 32);
    unsigned rA2 = (unsigned)__shfl_xor((int)(g1 ? U[4] : U[6]), 32);
    unsigned rA3 = (unsigned)__shfl_xor((int)(g1 ? U[5] : U[7]), 32);
    unsigned v2_000 = g1 ? rA0 : U[0];
    unsigned v2_001 = g1 ? rA1 : U[1];
    unsigned v2_010 = g1 ? U[2] : rA0;
    unsigned v2_011 = g1 ? U[3] : rA1;
    unsigned v2_100 = g1 ? rA2 : U[4];
    unsigned v2_101 = g1 ? rA3 : U[5];
    unsigned v2_110 = g1 ? U[6] : rA2;
    unsigned v2_111 = g1 ? U[7] : rA3;
    // butterfly stage B (xor 16, toggles g0): send c2 == !g0
    unsigned rB0 = (unsigned)__shfl_xor((int)(g0 ? v2_000 : v2_010), 16);
    unsigned rB1 = (unsigned)__shfl_xor((int)(g0 ? v2_001 : v2_011), 16);
    unsigned rB2 = (unsigned)__shfl_xor((int)(g0 ? v2_100 : v2_110), 16);
    unsigned rB3 = (unsigned)__shfl_xor((int)(g0 ? v2_101 : v2_111), 16);
    u32x4 t0v, t1v;
    t0v[0] = g0 ? rB0 : v2_000;
    t0v[1] = g0 ? rB1 : v2_001;
    t0v[2] = g0 ? v2_010 : rB0;
    t0v[3] = g0 ? v2_011 : rB1;
    t1v[0] = g0 ? rB2 : v2_100;
    t1v[1] = g0 ? rB3 : v2_101;
    t1v[2] = g0 ? v2_110 : rB2;
    t1v[3] = g0 ? v2_111 : rB3;
    bf16x8 pb0 = __builtin_bit_cast(bf16x8, t0v);  // B-frag P^T, kv-slice kk=0
    bf16x8 pb1 = __builtin_bit_cast(bf16x8, t1v);  // kk=1

    // PV swapped: oacc[n] += V^T-frag(dh rows n*16+lr) * P^T-frag
#pragma unroll
    for (int kk = 0; kk < 2; ++kk) {
      const bf16x8 pb = kk ? pb1 : pb0;
#pragma unroll
      for (int n = 0; n < 4; ++n) {
        const int r = n * 16 + lr;
        const int sl = (r * 8 + kk * 4 + g) ^ (r & 7);
        bf16x8 av = *(const bf16x8*)(&Vs[buf][sl * 8]);
        oacc[n] = __builtin_amdgcn_mfma_f32_16x16x32_bf16(av, pb, oacc[n], 0, 0, 0);
      }
    }
    __syncthreads();                         // prefetch landed + LDS safe to overwrite
    buf ^= 1;
  }

  if (u < 32) {
    // split block: write unnormalized partials (bf16) + (m,l)
    const int pr = G * 1024 + (qt - 16) * 64 + w * 16 + lr;
    bf16* oprow = OP + (size_t)(spl * 32768 + pr) * 64;
#pragma unroll
    for (int n = 0; n < 4; ++n) {
      bf16x4 o4;
#pragma unroll
      for (int i = 0; i < 4; ++i) o4[i] = (bf16)oacc[n][i];
      *(bf16x4*)(oprow + n * 16 + g * 4) = o4;
    }
    if (lane < 16) ML[spl * 32768 + pr] = make_float2(m_i, l_i);
  } else {
    const float li = 1.f / l_i;
    bf16* zrow = Z + ((size_t)(b * 2048 + qg) * 16 + hh) * 64;
#pragma unroll
    for (int n = 0; n < 4; ++n) {
      bf16x4 o4;
#pragma unroll
      for (int i = 0; i < 4; ++i) o4[i] = (bf16)(oacc[n][i] * li);
      *(bf16x4*)(zrow + n * 16 + g * 4) = o4;  // dh = n*16 + 4g + i
    }
  }
}

// ---------------- combine split partials into Z (rows q >= 1024 of each (b,h)) --------
__global__ __launch_bounds__(256)
void combine_kernel(const bf16* __restrict__ OP, const float2* __restrict__ ML,
                    bf16* __restrict__ Z) {
  const int id = blockIdx.x * 256 + threadIdx.x;   // 262144 = 32768 rows x 8 chunks
  const int pr = id >> 3, d8 = id & 7;
  const float2 ml0 = ML[pr], ml1 = ML[32768 + pr];
  const float m = fmaxf(ml0.x, ml1.x);
  const float w0 = __expf(ml0.x - m), w1 = __expf(ml1.x - m);
  const float inv = 1.f / (ml0.y * w0 + ml1.y * w1);
  const bf16x8 a = *(const bf16x8*)(OP + (size_t)pr * 64 + d8 * 8);
  const bf16x8 c = *(const bf16x8*)(OP + ((size_t)32768 + pr) * 64 + d8 * 8);
  bf16x8 o;
#pragma unroll
  for (int j = 0; j < 8; ++j)
    o[j] = (bf16)(((float)a[j] * w0 + (float)c[j] * w1) * inv);
  const int bh = pr >> 10, qr = pr & 1023;
  const int bb = bh >> 4, hq = bh & 15;
  *(bf16x8*)(Z + (((size_t)(bb * 2048 + 1024 + qr)) * 16 + hq) * 64 + d8 * 8) = o;
}

// ---------------- launcher ----------------
extern "C" void kernel_launch(void* const* d_in, const int* in_sizes, int n_in,
                              void* d_out, int out_size, void* d_ws, size_t ws_size,
                              hipStream_t stream) {
  const float* x  = (const float*)d_in[0];
  const float* WQ = (const float*)d_in[1];
  const float* WK = (const float*)d_in[2];
  const float* WV = (const float*)d_in[3];
  const float* WO = (const float*)d_in[4];
  const float* bQ = (const float*)d_in[5];
  const float* bK = (const float*)d_in[6];
  const float* bV = (const float*)d_in[7];
  const float* bO = (const float*)d_in[8];
  float* out = (float*)d_out;

  char* ws = (char*)d_ws;
  bf16* xb    = (bf16*)(ws);                        // 8 MB  [4096,1024]   (reused: OP)
  bf16* Wqkv  = (bf16*)(ws + (8u << 20));           // 6 MB  [3072,1024]   (reused: ML)
  bf16* Wo2   = (bf16*)(ws + (14u << 20));          // 2 MB  [1024,1024]
  bf16* Qb    = (bf16*)(ws + (16u << 20));          // 8 MB  [B,H,S,DH]
  bf16* Kb    = (bf16*)(ws + (24u << 20));          // 8 MB  [B,H,S,DH]
  bf16* Vtb   = (bf16*)(ws + (32u << 20));          // 8 MB  [B,H,DH,S]
  bf16* Zb    = (bf16*)(ws + (40u << 20));          // 8 MB  [4096,1024]
  float* biasq = (float*)(ws + (48u << 20));        // 12 KB [3072]
  // attn partials overlay regions consumed before attn runs (stream-ordered):
  bf16* OP    = (bf16*)(ws);                        // 8 MB  [2][32768][64] bf16
  float2* ML  = (float2*)(ws + (8u << 20));         // 0.5MB [2][32768] (m,l)

  prep_all<<<2048, 256, 0, stream>>>(x, WQ, WK, WV, WO, bQ, bK, bV, xb, Wqkv, Wo2, biasq);
  gemm_bt<0><<<512, 256, 0, stream>>>(xb, Wqkv, biasq, Qb, Kb, Vtb, nullptr,
                                      4096, 3072, 1024);
  attn_kernel<<<1536, 256, 0, stream>>>(Qb, Kb, Vtb, Zb, OP, ML);
  combine_kernel<<<1024, 256, 0, stream>>>(OP, ML, Zb);
  gemm_bt<1><<<256, 256, 0, stream>>>(Zb, Wo2, bO, nullptr, nullptr, nullptr, out,
                                      4096, 1024, 1024);
}